// Round 1
// baseline (423.355 us; speedup 1.0000x reference)
//
#include <hip/hip_runtime.h>

#define NFFT 1024
#define NT   256
// LDS swizzle: pad every 32 floats by 1 to break power-of-2 stride conflicts
__device__ __forceinline__ int swz(int a) { return a + (a >> 5); }

// One radix-4 Stockham stage (inverse sign). Reads x (swizzled), writes y (swizzled).
// L = current "l" (N/(4*m)), M = current "m".  Thread t does butterfly (j = t/M, k = t%M).
template<int L, int M>
__device__ __forceinline__ void stage(const float* __restrict__ xr,
                                      const float* __restrict__ xi,
                                      float* __restrict__ yr,
                                      float* __restrict__ yi,
                                      int t) {
    const int k  = t & (M - 1);
    const int j  = t / M;
    const int rb = swz(t);            // k + j*M == t ; stride L*M = 256 -> +264 swizzled

    float c0r = xr[rb];        float c0i = xi[rb];
    float c1r = xr[rb + 264];  float c1i = xi[rb + 264];
    float c2r = xr[rb + 528];  float c2i = xi[rb + 528];
    float c3r = xr[rb + 792];  float c3i = xi[rb + 792];

    float d0r = c0r + c2r, d0i = c0i + c2i;
    float d1r = c0r - c2r, d1i = c0i - c2i;
    float d2r = c1r + c3r, d2i = c1i + c3i;
    // d3 = +i*(c1 - c3)   (inverse transform)
    float d3r = c3i - c1i, d3i = c1r - c3r;

    float e0r = d0r + d2r, e0i = d0i + d2i;
    float e2r = d0r - d2r, e2i = d0i - d2i;
    float e1r = d1r + d3r, e1i = d1i + d3i;
    float e3r = d1r - d3r, e3i = d1i - d3i;

    float o1r, o1i, o2r, o2i, o3r, o3i;
    if (L == 1) {
        o1r = e1r; o1i = e1i; o2r = e2r; o2i = e2i; o3r = e3r; o3i = e3i;
    } else {
        const float base_ang = 6.28318530717958647692f / (float)(4 * L);
        float ang = base_ang * (float)j;     // w1 = exp(+i*ang)
        float w1i, w1r;
        __sincosf(ang, &w1i, &w1r);
        float w2r = w1r * w1r - w1i * w1i;
        float w2i = 2.0f * w1r * w1i;
        float w3r = w2r * w1r - w2i * w1i;
        float w3i = w2r * w1i + w2i * w1r;
        o1r = w1r * e1r - w1i * e1i;  o1i = w1r * e1i + w1i * e1r;
        o2r = w2r * e2r - w2i * e2i;  o2i = w2r * e2i + w2i * e2r;
        o3r = w3r * e3r - w3i * e3i;  o3i = w3r * e3i + w3i * e3r;
    }

    const int wb = k + 4 * j * M;
    yr[swz(wb)]         = e0r;  yi[swz(wb)]         = e0i;
    yr[swz(wb + M)]     = o1r;  yi[swz(wb + M)]     = o1i;
    yr[swz(wb + 2 * M)] = o2r;  yi[swz(wb + 2 * M)] = o2i;
    yr[swz(wb + 3 * M)] = o3r;  yi[swz(wb + 3 * M)] = o3i;
}

__global__ __launch_bounds__(NT, 8) void ifft1024_kernel(
        const float* __restrict__ re, const float* __restrict__ im,
        float* __restrict__ out, size_t im_out_off) {
    __shared__ float Ar[1056], Ai[1056], Br[1056], Bi[1056];

    const int t = threadIdx.x;
    const size_t base = (size_t)blockIdx.x * NFFT;

    float4 r4 = *(const float4*)(re + base + 4 * t);
    float4 i4 = *(const float4*)(im + base + 4 * t);
    const int p = swz(4 * t);   // 4t..4t+3 stay contiguous after swizzle
    Ar[p] = r4.x; Ar[p + 1] = r4.y; Ar[p + 2] = r4.z; Ar[p + 3] = r4.w;
    Ai[p] = i4.x; Ai[p + 1] = i4.y; Ai[p + 2] = i4.z; Ai[p + 3] = i4.w;
    __syncthreads();

    stage<256, 1 >(Ar, Ai, Br, Bi, t); __syncthreads();
    stage<64,  4 >(Br, Bi, Ar, Ai, t); __syncthreads();
    stage<16,  16>(Ar, Ai, Br, Bi, t); __syncthreads();
    stage<4,   64>(Br, Bi, Ar, Ai, t); __syncthreads();
    stage<1,  256>(Ar, Ai, Br, Bi, t); __syncthreads();

    const float s = 1.0f / 1024.0f;   // IFFT normalization
    float4 ro, io;
    ro.x = Br[p] * s; ro.y = Br[p + 1] * s; ro.z = Br[p + 2] * s; ro.w = Br[p + 3] * s;
    io.x = Bi[p] * s; io.y = Bi[p + 1] * s; io.z = Bi[p + 2] * s; io.w = Bi[p + 3] * s;

    *(float4*)(out + base + 4 * t)              = ro;
    *(float4*)(out + im_out_off + base + 4 * t) = io;
}

extern "C" void kernel_launch(void* const* d_in, const int* in_sizes, int n_in,
                              void* d_out, int out_size, void* d_ws, size_t ws_size,
                              hipStream_t stream) {
    const float* re = (const float*)d_in[0];
    const float* im = (const float*)d_in[1];
    float* out = (float*)d_out;
    const int rows = in_sizes[0] / NFFT;          // 8*4096 = 32768
    const size_t im_off = (size_t)in_sizes[0];    // output: [re | im] concatenated

    hipLaunchKernelGGL(ifft1024_kernel, dim3(rows), dim3(NT), 0, stream,
                       re, im, out, im_off);
}